// Round 6
// baseline (10223.000 us; speedup 1.0000x reference)
//
#include <hip/hip_runtime.h>

// Problem constants (from setup_inputs)
#define ND0 90112
#define ND1 8192
#define NDT (ND0 + ND1)
#define NE0 1351680
#define NE1 81920
#define NET (NE0 + NE1)
#define F_IN 128
#define HID 256
#define F_OUT 128

typedef __attribute__((ext_vector_type(8))) short short8;
typedef __attribute__((ext_vector_type(4))) float f32x4;

__device__ inline ushort f2bf(float f) {
    unsigned u = __float_as_uint(f);
    return (ushort)((u + 0x7fffu + ((u >> 16) & 1u)) >> 16);
}
__device__ inline float bf2f(ushort h) {
    return __uint_as_float(((unsigned)h) << 16);
}

// ------------------------------------------------------------------
// Degree histogram over combined [layer0 | layer1] dst space
// ------------------------------------------------------------------
__global__ void hist_all_k(const int* __restrict__ edst0, const int* __restrict__ edst1,
                           int* __restrict__ cnt) {
    int e = blockIdx.x * 256 + threadIdx.x;
    if (e < NE0)
        atomicAdd(&cnt[edst0[e]], 1);
    else if (e < NET)
        atomicAdd(&cnt[ND0 + edst1[e - NE0]], 1);
}

// ------------------------------------------------------------------
// Merged weight transpose+convert for both layers
// ------------------------------------------------------------------
__global__ void wtrans_all_k(const float* __restrict__ Wl0, const float* __restrict__ Wr0,
                             const float* __restrict__ Wl1, const float* __restrict__ Wr1,
                             ushort* __restrict__ Bt0, ushort* __restrict__ Bt1) {
    int idx = blockIdx.x * 256 + threadIdx.x;
    constexpr int N0 = HID * 2 * F_IN;  // 65536
    if (idx < N0) {
        int K2 = 2 * F_IN;
        int n = idx / K2, k = idx - n * K2;
        float v = (k < F_IN) ? Wl0[(size_t)k * HID + n] : Wr0[(size_t)(k - F_IN) * HID + n];
        Bt0[idx] = f2bf(v);
    } else {
        int j = idx - N0;  // F_OUT * 2 * HID = 65536
        int K2 = 2 * HID;
        int n = j / K2, k = j - n * K2;
        float v = (k < HID) ? Wl1[(size_t)k * F_OUT + n] : Wr1[(size_t)(k - HID) * F_OUT + n];
        Bt1[j] = f2bf(v);
    }
}

// ------------------------------------------------------------------
// Edge-parallel scatter-add, layer 1: acc0[dst] += x_all[n_id[src]]
// 4 threads/edge, 32 floats (128 B) each. Edges in memory order.
// ------------------------------------------------------------------
__global__ __launch_bounds__(256) void eagg0_k(
    const float* __restrict__ X, const int* __restrict__ esrc,
    const int* __restrict__ edst, const int* __restrict__ nid,
    float* __restrict__ acc) {
    int idx = blockIdx.x * 256 + threadIdx.x;
    int e = idx >> 2, q = idx & 3;
    if (e >= NE0) return;
    int s = nid[esrc[e]];
    int d = edst[e];
    const float* rp = &X[(size_t)s * F_IN + q * 32];
    float* ap = &acc[(size_t)d * F_IN + q * 32];
#pragma unroll
    for (int i = 0; i < 32; i += 4) {
        float4 v = *(const float4*)(rp + i);
        unsafeAtomicAdd(ap + i + 0, v.x);
        unsafeAtomicAdd(ap + i + 1, v.y);
        unsafeAtomicAdd(ap + i + 2, v.z);
        unsafeAtomicAdd(ap + i + 3, v.w);
    }
}

// ------------------------------------------------------------------
// Edge-parallel scatter-add, layer 2: acc1[dst] += h[src] (bf16 -> fp32)
// ------------------------------------------------------------------
__global__ __launch_bounds__(256) void eagg1_k(
    const ushort* __restrict__ H, const int* __restrict__ esrc,
    const int* __restrict__ edst, float* __restrict__ acc) {
    int idx = blockIdx.x * 256 + threadIdx.x;
    int e = idx >> 2, q = idx & 3;
    if (e >= NE1) return;
    int s = esrc[e];
    int d = edst[e];
    const ushort* rp = &H[(size_t)s * HID + q * 64];
    float* ap = &acc[(size_t)d * HID + q * 64];
#pragma unroll
    for (int i = 0; i < 64; i += 8) {
        short8 v = *(const short8*)(rp + i);
#pragma unroll
        for (int j = 0; j < 8; ++j) unsafeAtomicAdd(ap + i + j, bf2f((ushort)v[j]));
    }
}

// ------------------------------------------------------------------
// Layer-1 GEMM: h = relu([acc0*inv | x_all[nid]] @ Bt0^T + b0), bf16 out
// BM=128 BN=64 K=256, 256 thr (4 waves 2x2), 16x16x32 MFMA.
// ------------------------------------------------------------------
__global__ __launch_bounds__(256) void gemm1_k(
    const float* __restrict__ acc0, const int* __restrict__ cnt,
    const float* __restrict__ X, const int* __restrict__ nid,
    const ushort* __restrict__ Bt, const float* __restrict__ bias,
    ushort* __restrict__ H) {
    __shared__ ushort As[128][72];
    __shared__ ushort Bs[64][72];
    __shared__ float s_inv[128];
    __shared__ int s_nid[128];

    int t = threadIdx.x;
    int row0 = blockIdx.x * 128, col0 = blockIdx.y * 64;
    if (t < 128) {
        int c = cnt[row0 + t];
        s_inv[t] = 1.f / (float)(c > 0 ? c : 1);
        s_nid[t] = nid[row0 + t];
    }
    __syncthreads();

    int lane = t & 63, w = t >> 6, wm = w >> 1, wn = w & 1;
    int lr = lane & 15, lk = (lane >> 4) * 8;
    int ar = t >> 1, ac = (t & 1) * 32;  // A stage: 2 thr/row, 32 elems
    int bn = t >> 2, bc = (t & 3) * 16;  // B stage: 4 thr/row, 16 elems

    f32x4 acc[4][2] = {};

    for (int k0 = 0; k0 < 256; k0 += 64) {
        float av[32];
        if (k0 < 128) {
            const float* ap = &acc0[(size_t)(row0 + ar) * F_IN + k0 + ac];
            float inv = s_inv[ar];
#pragma unroll
            for (int i = 0; i < 32; i += 4) {
                float4 v = *(const float4*)(ap + i);
                av[i + 0] = v.x * inv; av[i + 1] = v.y * inv;
                av[i + 2] = v.z * inv; av[i + 3] = v.w * inv;
            }
        } else {
            const float* gp = &X[(size_t)s_nid[ar] * F_IN + (k0 - 128) + ac];
#pragma unroll
            for (int i = 0; i < 32; i += 4) {
                float4 v = *(const float4*)(gp + i);
                av[i + 0] = v.x; av[i + 1] = v.y;
                av[i + 2] = v.z; av[i + 3] = v.w;
            }
        }
        short8 bv0 = *(const short8*)&Bt[(size_t)(col0 + bn) * 256 + k0 + bc];
        short8 bv1 = *(const short8*)&Bt[(size_t)(col0 + bn) * 256 + k0 + bc + 8];
        __syncthreads();  // prior MFMA reads done
#pragma unroll
        for (int i = 0; i < 32; i += 8) {
            short8 o;
#pragma unroll
            for (int j = 0; j < 8; ++j) o[j] = (short)f2bf(av[i + j]);
            *(short8*)&As[ar][ac + i] = o;
        }
        *(short8*)&Bs[bn][bc] = bv0;
        *(short8*)&Bs[bn][bc + 8] = bv1;
        __syncthreads();
#pragma unroll
        for (int ks = 0; ks < 64; ks += 32) {
            short8 bf0 = *(const short8*)&Bs[wn * 32 + lr][ks + lk];
            short8 bf1 = *(const short8*)&Bs[wn * 32 + 16 + lr][ks + lk];
#pragma unroll
            for (int mi = 0; mi < 4; ++mi) {
                short8 af = *(const short8*)&As[wm * 64 + mi * 16 + lr][ks + lk];
                acc[mi][0] = __builtin_amdgcn_mfma_f32_16x16x32_bf16(af, bf0, acc[mi][0], 0, 0, 0);
                acc[mi][1] = __builtin_amdgcn_mfma_f32_16x16x32_bf16(af, bf1, acc[mi][1], 0, 0, 0);
            }
        }
    }

    int orow = row0 + wm * 64;
    int ocol = col0 + wn * 32;
#pragma unroll
    for (int mi = 0; mi < 4; ++mi) {
#pragma unroll
        for (int ni = 0; ni < 2; ++ni) {
            int c = ocol + ni * 16 + lr;
            float bi = bias[c];
#pragma unroll
            for (int j = 0; j < 4; ++j) {
                int r = orow + mi * 16 + (lane >> 4) * 4 + j;
                float v = acc[mi][ni][j] + bi;
                v = fmaxf(v, 0.f);
                H[(size_t)r * HID + c] = f2bf(v);
            }
        }
    }
}

// ------------------------------------------------------------------
// Layer-2 GEMM: out = [acc1*inv | h] @ Bt1^T + b1, fp32 out
// BM=64 BN=64 K=512, 256 thr (4 waves 2x2).
// ------------------------------------------------------------------
__global__ __launch_bounds__(256) void gemm2_k(
    const float* __restrict__ acc1, const int* __restrict__ cnt,
    const ushort* __restrict__ H, const ushort* __restrict__ Bt,
    const float* __restrict__ bias, float* __restrict__ out) {
    __shared__ ushort As[64][72];
    __shared__ ushort Bs[64][72];
    __shared__ float s_inv[64];

    int t = threadIdx.x;
    int row0 = blockIdx.x * 64, col0 = blockIdx.y * 64;
    if (t < 64) {
        int c = cnt[ND0 + row0 + t];
        s_inv[t] = 1.f / (float)(c > 0 ? c : 1);
    }
    __syncthreads();

    int lane = t & 63, w = t >> 6, wm = w >> 1, wn = w & 1;
    int lr = lane & 15, lk = (lane >> 4) * 8;
    int ar = t >> 2, ac = (t & 3) * 16;  // A stage: 4 thr/row, 16 elems
    int bn = t >> 2, bc = (t & 3) * 16;

    f32x4 acc[2][2] = {};

    for (int k0 = 0; k0 < 512; k0 += 64) {
        ushort ov[16];
        if (k0 < 256) {
            const float* ap = &acc1[(size_t)(row0 + ar) * HID + k0 + ac];
            float inv = s_inv[ar];
#pragma unroll
            for (int i = 0; i < 16; i += 4) {
                float4 v = *(const float4*)(ap + i);
                ov[i + 0] = f2bf(v.x * inv); ov[i + 1] = f2bf(v.y * inv);
                ov[i + 2] = f2bf(v.z * inv); ov[i + 3] = f2bf(v.w * inv);
            }
        } else {
            const ushort* hp = &H[(size_t)(row0 + ar) * HID + (k0 - 256) + ac];
            short8 v0 = *(const short8*)(hp);
            short8 v1 = *(const short8*)(hp + 8);
#pragma unroll
            for (int j = 0; j < 8; ++j) { ov[j] = (ushort)v0[j]; ov[8 + j] = (ushort)v1[j]; }
        }
        short8 bv0 = *(const short8*)&Bt[(size_t)(col0 + bn) * 512 + k0 + bc];
        short8 bv1 = *(const short8*)&Bt[(size_t)(col0 + bn) * 512 + k0 + bc + 8];
        __syncthreads();
        *(short8*)&As[ar][ac] = *(short8*)&ov[0];
        *(short8*)&As[ar][ac + 8] = *(short8*)&ov[8];
        *(short8*)&Bs[bn][bc] = bv0;
        *(short8*)&Bs[bn][bc + 8] = bv1;
        __syncthreads();
#pragma unroll
        for (int ks = 0; ks < 64; ks += 32) {
            short8 bf0 = *(const short8*)&Bs[wn * 32 + lr][ks + lk];
            short8 bf1 = *(const short8*)&Bs[wn * 32 + 16 + lr][ks + lk];
#pragma unroll
            for (int mi = 0; mi < 2; ++mi) {
                short8 af = *(const short8*)&As[wm * 32 + mi * 16 + lr][ks + lk];
                acc[mi][0] = __builtin_amdgcn_mfma_f32_16x16x32_bf16(af, bf0, acc[mi][0], 0, 0, 0);
                acc[mi][1] = __builtin_amdgcn_mfma_f32_16x16x32_bf16(af, bf1, acc[mi][1], 0, 0, 0);
            }
        }
    }

    int orow = row0 + wm * 32;
    int ocol = col0 + wn * 32;
#pragma unroll
    for (int mi = 0; mi < 2; ++mi) {
#pragma unroll
        for (int ni = 0; ni < 2; ++ni) {
            int c = ocol + ni * 16 + lr;
            float bi = bias[c];
#pragma unroll
            for (int j = 0; j < 4; ++j) {
                int r = orow + mi * 16 + (lane >> 4) * 4 + j;
                out[(size_t)r * F_OUT + c] = acc[mi][ni][j] + bi;
            }
        }
    }
}

// ------------------------------------------------------------------
extern "C" void kernel_launch(void* const* d_in, const int* in_sizes, int n_in,
                              void* d_out, int out_size, void* d_ws, size_t ws_size,
                              hipStream_t stream) {
    const float* x_all = (const float*)d_in[0];
    const int* n_id = (const int*)d_in[1];
    const int* esrc0 = (const int*)d_in[2];
    const int* edst0 = (const int*)d_in[3];
    const int* esrc1 = (const int*)d_in[4];
    const int* edst1 = (const int*)d_in[5];
    const float* W_l0 = (const float*)d_in[6];
    const float* b_l0 = (const float*)d_in[7];
    const float* W_r0 = (const float*)d_in[8];
    const float* W_l1 = (const float*)d_in[9];
    const float* b_l1 = (const float*)d_in[10];
    const float* W_r1 = (const float*)d_in[11];

    char* ws = (char*)d_ws;
    size_t off = 0;
    auto alloc = [&](size_t bytes) {
        off = (off + 255) & ~(size_t)255;
        void* p = ws + off;
        off += bytes;
        return p;
    };
    // zero-init region: [acc0 | acc1 | cnt] contiguous, one memset
    float* acc0 = (float*)alloc((size_t)ND0 * F_IN * 4);
    float* acc1 = (float*)alloc((size_t)ND1 * HID * 4);
    int* cnt = (int*)alloc((size_t)NDT * 4);
    size_t zero_bytes = off;  // all allocations so far are 256-aligned from 0
    ushort* h = (ushort*)alloc((size_t)ND0 * HID * 2);
    ushort* Bt0 = (ushort*)alloc((size_t)HID * (2 * F_IN) * 2);
    ushort* Bt1 = (ushort*)alloc((size_t)F_OUT * (2 * HID) * 2);

    hipMemsetAsync(ws, 0, zero_bytes, stream);

    wtrans_all_k<<<512, 256, 0, stream>>>(W_l0, W_r0, W_l1, W_r1, Bt0, Bt1);
    hist_all_k<<<NET / 256, 256, 0, stream>>>(edst0, edst1, cnt);

    // ---------------- Layer 1 ----------------
    eagg0_k<<<(NE0 * 4) / 256, 256, 0, stream>>>(x_all, esrc0, edst0, n_id, acc0);
    gemm1_k<<<dim3(ND0 / 128, HID / 64), 256, 0, stream>>>(acc0, cnt, x_all, n_id,
                                                           Bt0, b_l0, h);

    // ---------------- Layer 2 ----------------
    eagg1_k<<<(NE1 * 4) / 256, 256, 0, stream>>>(h, esrc1, edst1, acc1);
    gemm2_k<<<dim3(ND1 / 64, F_OUT / 64), 256, 0, stream>>>(acc1, cnt, h, Bt1,
                                                            b_l1, (float*)d_out);
}

// Round 7
// 593.561 us; speedup vs baseline: 17.2232x; 17.2232x over previous
//
#include <hip/hip_runtime.h>

// Problem constants (from setup_inputs)
#define ND0 90112
#define ND1 8192
#define NDT (ND0 + ND1)         // 98304 combined dst space
#define NE0 1351680
#define NE1 81920
#define NET (NE0 + NE1)
#define F_IN 128
#define HID 256
#define F_OUT 128

// DIAGNOSTIC: fused1 repeats its full body this many times (idempotent).
// T_fused1 = (dur_this_round - dur_round5) / (FUSED1_REPS - 1)
#define FUSED1_REPS 3

typedef __attribute__((ext_vector_type(8))) short short8;
typedef __attribute__((ext_vector_type(4))) float f32x4;

__device__ inline ushort f2bf(float f) {
    unsigned u = __float_as_uint(f);
    return (ushort)((u + 0x7fffu + ((u >> 16) & 1u)) >> 16);
}
__device__ inline float bf2f(ushort h) {
    return __uint_as_float(((unsigned)h) << 16);
}

// ------------------------------------------------------------------
// Combined CSR build over [layer0 dsts | layer1 dsts]
// ------------------------------------------------------------------
__global__ void hist_all_k(const int* __restrict__ edst0, const int* __restrict__ edst1,
                           int* __restrict__ cnt) {
    int e = blockIdx.x * 256 + threadIdx.x;
    if (e < NE0)
        atomicAdd(&cnt[edst0[e]], 1);
    else if (e < NET)
        atomicAdd(&cnt[ND0 + edst1[e - NE0]], 1);
}

// 1024-elem chunks: per-chunk exclusive scan + chunk totals
__global__ void scan_part_k(const int* __restrict__ in, int* __restrict__ out,
                            int* __restrict__ bsum, int n) {
    __shared__ int sh[256];
    int base = blockIdx.x * 1024;
    int t = threadIdx.x;
    int v[4];
    int s = 0;
#pragma unroll
    for (int i = 0; i < 4; ++i) {
        int idx = base + t * 4 + i;
        v[i] = (idx < n) ? in[idx] : 0;
        s += v[i];
    }
    sh[t] = s;
    __syncthreads();
    for (int off = 1; off < 256; off <<= 1) {
        int x = (t >= off) ? sh[t - off] : 0;
        __syncthreads();
        sh[t] += x;
        __syncthreads();
    }
    int excl = (t == 0) ? 0 : sh[t - 1];
    if (t == 255 && bsum) bsum[blockIdx.x] = sh[255];
#pragma unroll
    for (int i = 0; i < 4; ++i) {
        int idx = base + t * 4 + i;
        if (idx < n) out[idx] = excl;
        excl += v[i];
    }
}

__global__ void scan_add_k(int* __restrict__ out, const int* __restrict__ boff, int n) {
    int i = blockIdx.x * 256 + threadIdx.x;
    if (i < n) out[i] += boff[i >> 10];
}

// scatter both layers; layer0 src pre-mapped through n_id
__global__ void scatter_all_k(const int* __restrict__ esrc0, const int* __restrict__ edst0,
                              const int* __restrict__ esrc1, const int* __restrict__ edst1,
                              const int* __restrict__ nid, const int* __restrict__ rstart,
                              int* __restrict__ cursor, int* __restrict__ csr) {
    int e = blockIdx.x * 256 + threadIdx.x;
    if (e >= NET) return;
    int d, s;
    if (e < NE0) {
        d = edst0[e];
        s = nid[esrc0[e]];
    } else {
        int e1 = e - NE0;
        d = ND0 + edst1[e1];
        s = esrc1[e1];
    }
    int pos = rstart[d] + atomicAdd(&cursor[d], 1);
    csr[pos] = s;
}

// ------------------------------------------------------------------
// Merged weight transpose+convert for both layers
// ------------------------------------------------------------------
__global__ void wtrans_all_k(const float* __restrict__ Wl0, const float* __restrict__ Wr0,
                             const float* __restrict__ Wl1, const float* __restrict__ Wr1,
                             ushort* __restrict__ Bt0, ushort* __restrict__ Bt1) {
    int idx = blockIdx.x * 256 + threadIdx.x;
    constexpr int N0 = HID * 2 * F_IN;  // 65536
    if (idx < N0) {
        int K2 = 2 * F_IN;
        int n = idx / K2, k = idx - n * K2;
        float v = (k < F_IN) ? Wl0[(size_t)k * HID + n] : Wr0[(size_t)(k - F_IN) * HID + n];
        Bt0[idx] = f2bf(v);
    } else {
        int j = idx - N0;  // F_OUT * 2 * HID = 65536
        int K2 = 2 * HID;
        int n = j / K2, k = j - n * K2;
        float v = (k < HID) ? Wl1[(size_t)k * F_OUT + n] : Wr1[(size_t)(k - HID) * F_OUT + n];
        Bt1[j] = f2bf(v);
    }
}

// ------------------------------------------------------------------
// FUSED layer-1: aggregate (mean) + x_dst gather -> LDS A-tile -> MFMA GEMM
//   h[128 rows][256] = relu([mean | x_dst] @ Bt0^T + bias)
// DIAGNOSTIC BUILD: whole body repeated FUSED1_REPS times (idempotent).
// ------------------------------------------------------------------
__global__ __launch_bounds__(512, 4) void fused1_k(
    const float* __restrict__ X, const int* __restrict__ csr,
    const int* __restrict__ rstart, const int* __restrict__ cnt,
    const int* __restrict__ nid, const ushort* __restrict__ Bt,
    const float* __restrict__ bias, ushort* __restrict__ C) {
    __shared__ ushort As[128][264];  // [row][mean(0..127) | xdst(128..255)], +8 pad
    __shared__ ushort Bs[64][72];
    __shared__ int s_beg[128], s_num[128];

    int t = threadIdx.x;
    int row0 = blockIdx.x * 128;

    if (t < 128) {
        s_beg[t] = rstart[row0 + t];
        s_num[t] = cnt[row0 + t];
    }

#pragma unroll 1
    for (int rep = 0; rep < FUSED1_REPS; ++rep) {
        __syncthreads();  // reps reuse LDS; also covers s_beg/s_num on rep 0

        // ---------- phase 1a: x_dst gather ----------
        {
            int row = t >> 2, q = t & 3;
            int gr = nid[row0 + row];
            const float* gp = &X[(size_t)gr * F_IN + q * 32];
#pragma unroll
            for (int i = 0; i < 4; ++i) {
                float4 v0 = *(const float4*)(gp + i * 8);
                float4 v1 = *(const float4*)(gp + i * 8 + 4);
                short8 o;
                o[0] = (short)f2bf(v0.x); o[1] = (short)f2bf(v0.y);
                o[2] = (short)f2bf(v0.z); o[3] = (short)f2bf(v0.w);
                o[4] = (short)f2bf(v1.x); o[5] = (short)f2bf(v1.y);
                o[6] = (short)f2bf(v1.z); o[7] = (short)f2bf(v1.w);
                *(short8*)&As[row][F_IN + q * 32 + i * 8] = o;
            }
        }

        // ---------- phase 1b: edge aggregation, 4 passes of 32 rows ----------
        {
            int q = t & 3;             // col chunk (32 floats)
            int slot = (t >> 2) & 3;   // edge slot (lane bits 2..3)
            int rloc = t >> 4;         // row within pass [0,32)
#pragma unroll 1
            for (int pass = 0; pass < 4; ++pass) {
                int row = pass * 32 + rloc;
                int beg = s_beg[row], num = s_num[row];
                float acc[32] = {};
#pragma unroll 1
                for (int e = slot; e < num; e += 4) {
                    int r = csr[beg + e];
                    const float* rp = &X[(size_t)r * F_IN + q * 32];
#pragma unroll
                    for (int i = 0; i < 8; ++i) {
                        float4 v = *(const float4*)(rp + i * 4);
                        acc[i * 4 + 0] += v.x;
                        acc[i * 4 + 1] += v.y;
                        acc[i * 4 + 2] += v.z;
                        acc[i * 4 + 3] += v.w;
                    }
                }
#pragma unroll
                for (int i = 0; i < 32; ++i) {
                    acc[i] += __shfl_xor(acc[i], 4);
                    acc[i] += __shfl_xor(acc[i], 8);
                }
                if (slot == 0) {
                    float inv = 1.f / (float)((num > 0) ? num : 1);
#pragma unroll
                    for (int i = 0; i < 4; ++i) {
                        short8 o;
#pragma unroll
                        for (int j = 0; j < 8; ++j) o[j] = (short)f2bf(acc[i * 8 + j] * inv);
                        *(short8*)&As[row][q * 32 + i * 8] = o;
                    }
                }
            }
        }

        // ---------- phase 2: GEMM ----------
        int lane = t & 63;
        int w = t >> 6;
        int wm = w >> 2, wn2 = w & 3;  // 2(m) x 4(n) wave grid
        int lr = lane & 15, lj = lane >> 4;
        int bn = t >> 3, bk = (t & 7) * 8;

        for (int nt = 0; nt < 4; ++nt) {
            f32x4 acc2[4] = {};
            for (int k0 = 0; k0 < 256; k0 += 64) {
                short8 bv = *(const short8*)&Bt[(size_t)(nt * 64 + bn) * 256 + k0 + bk];
                __syncthreads();  // As writes done (1st iter); prior Bs reads done
                *(short8*)&Bs[bn][bk] = bv;
                __syncthreads();
#pragma unroll
                for (int ks = 0; ks < 64; ks += 32) {
                    short8 bf = *(const short8*)&Bs[wn2 * 16 + lr][ks + lj * 8];
#pragma unroll
                    for (int mi = 0; mi < 4; ++mi) {
                        short8 af = *(const short8*)&As[wm * 64 + mi * 16 + lr][k0 + ks + lj * 8];
                        acc2[mi] = __builtin_amdgcn_mfma_f32_16x16x32_bf16(af, bf, acc2[mi], 0, 0, 0);
                    }
                }
            }
            int c = nt * 64 + wn2 * 16 + lr;
            float bi = bias[c];
#pragma unroll
            for (int mi = 0; mi < 4; ++mi) {
#pragma unroll
                for (int j = 0; j < 4; ++j) {
                    int r = row0 + wm * 64 + mi * 16 + lj * 4 + j;
                    float v = acc2[mi][j] + bi;
                    v = fmaxf(v, 0.f);
                    C[(size_t)r * HID + c] = f2bf(v);
                }
            }
        }
        asm volatile("" ::: "memory");  // keep reps from folding
    }
}

// ------------------------------------------------------------------
// Mean aggregation (layer 2), vectorized 16B/lane, bf16 in.
// ------------------------------------------------------------------
template <int F>
__global__ __launch_bounds__(128) void agg_k(
    const ushort* __restrict__ Xh, const int* __restrict__ csr,
    const int* __restrict__ rstart, const int* __restrict__ cnt, int dofs,
    ushort* __restrict__ mean) {
    __shared__ float sh[128][8];
    int d = blockIdx.x;
    int t = threadIdx.x;
    int cg = t & 31, slot = t >> 5;
    int beg = rstart[dofs + d];
    int num = cnt[dofs + d];
    float acc[8] = {};
    for (int e = 0; e < num; e += 8) {
        int i0 = e + slot, i1 = e + 4 + slot;
        bool v0 = i0 < num, v1 = i1 < num;
        int r0 = v0 ? csr[beg + i0] : 0;
        int r1 = v1 ? csr[beg + i1] : 0;
        if (v0) {
            short8 x = *(const short8*)&Xh[(size_t)r0 * F + cg * 8];
#pragma unroll
            for (int i = 0; i < 8; ++i) acc[i] += bf2f((ushort)x[i]);
        }
        if (v1) {
            short8 x = *(const short8*)&Xh[(size_t)r1 * F + cg * 8];
#pragma unroll
            for (int i = 0; i < 8; ++i) acc[i] += bf2f((ushort)x[i]);
        }
    }
#pragma unroll
    for (int i = 0; i < 8; ++i) sh[t][i] = acc[i];
    __syncthreads();
    if (t < 32) {
        float inv = 1.f / (float)((num > 0) ? num : 1);
        short8 ov;
#pragma unroll
        for (int i = 0; i < 8; ++i) {
            float s = sh[t][i] + sh[t + 32][i] + sh[t + 64][i] + sh[t + 96][i];
            ov[i] = (short)f2bf(s * inv);
        }
        *(short8*)&mean[(size_t)d * F + t * 8] = ov;
    }
}

// ------------------------------------------------------------------
// bf16 MFMA concat-K GEMM (layer 2): C = [A0 | A1] @ Bt^T + bias
// ------------------------------------------------------------------
template <int BM, int KHALF, int NCOLS, bool RELU, bool OUT_BF16>
__global__ __launch_bounds__(256) void mgemm_k(
    const ushort* __restrict__ A0, const ushort* __restrict__ A1,
    const ushort* __restrict__ Bt, const float* __restrict__ bias,
    void* __restrict__ Cv, int M) {
    constexpr int MI = BM / 32;
    constexpr int TPR = 256 / BM;
    constexpr int AV = 64 / TPR / 8;
    __shared__ ushort As[BM][72];
    __shared__ ushort Bs[64][72];

    int t = threadIdx.x;
    int row0 = blockIdx.x * BM;
    int col0 = blockIdx.y * 64;
    int lane = t & 63;
    int w = t >> 6, wm = w >> 1, wn = w & 1;
    int lr = lane & 15;
    int lk = (lane >> 4) * 8;

    int ar = t / TPR, ac = (t % TPR) * (64 / TPR);
    int bn = t >> 2, bc = (t & 3) * 16;

    f32x4 acc[MI][2] = {};

    for (int k0 = 0; k0 < 2 * KHALF; k0 += 64) {
        const ushort* Asrc = (k0 < KHALF) ? A0 : A1;
        int kof = (k0 < KHALF) ? k0 : (k0 - KHALF);
        const ushort* ap = &Asrc[(size_t)(row0 + ar) * KHALF + kof + ac];
        const ushort* bp = &Bt[(size_t)(col0 + bn) * (2 * KHALF) + k0 + bc];
        short8 av[AV];
#pragma unroll
        for (int i = 0; i < AV; ++i) av[i] = *(const short8*)(ap + 8 * i);
        short8 bv0 = *(const short8*)(bp);
        short8 bv1 = *(const short8*)(bp + 8);
        __syncthreads();
#pragma unroll
        for (int i = 0; i < AV; ++i) *(short8*)&As[ar][ac + 8 * i] = av[i];
        *(short8*)&Bs[bn][bc + 0] = bv0;
        *(short8*)&Bs[bn][bc + 8] = bv1;
        __syncthreads();
#pragma unroll
        for (int ks = 0; ks < 64; ks += 32) {
            short8 bf0 = *(const short8*)&Bs[wn * 32 + lr][ks + lk];
            short8 bf1 = *(const short8*)&Bs[wn * 32 + 16 + lr][ks + lk];
#pragma unroll
            for (int mi = 0; mi < MI; ++mi) {
                short8 af = *(const short8*)&As[wm * (BM / 2) + mi * 16 + lr][ks + lk];
                acc[mi][0] = __builtin_amdgcn_mfma_f32_16x16x32_bf16(af, bf0, acc[mi][0], 0, 0, 0);
                acc[mi][1] = __builtin_amdgcn_mfma_f32_16x16x32_bf16(af, bf1, acc[mi][1], 0, 0, 0);
            }
        }
    }

    int orow = row0 + wm * (BM / 2);
    int ocol = col0 + wn * 32;
#pragma unroll
    for (int mi = 0; mi < MI; ++mi) {
#pragma unroll
        for (int ni = 0; ni < 2; ++ni) {
            int c = ocol + ni * 16 + lr;
            float bi = bias[c];
#pragma unroll
            for (int j = 0; j < 4; ++j) {
                int r = orow + mi * 16 + (lane >> 4) * 4 + j;
                float v = acc[mi][ni][j] + bi;
                if (RELU) v = fmaxf(v, 0.f);
                if (OUT_BF16)
                    ((ushort*)Cv)[(size_t)r * NCOLS + c] = f2bf(v);
                else
                    ((float*)Cv)[(size_t)r * NCOLS + c] = v;
            }
        }
    }
}

// ------------------------------------------------------------------
extern "C" void kernel_launch(void* const* d_in, const int* in_sizes, int n_in,
                              void* d_out, int out_size, void* d_ws, size_t ws_size,
                              hipStream_t stream) {
    const float* x_all = (const float*)d_in[0];
    const int* n_id = (const int*)d_in[1];
    const int* esrc0 = (const int*)d_in[2];
    const int* edst0 = (const int*)d_in[3];
    const int* esrc1 = (const int*)d_in[4];
    const int* edst1 = (const int*)d_in[5];
    const float* W_l0 = (const float*)d_in[6];
    const float* b_l0 = (const float*)d_in[7];
    const float* W_r0 = (const float*)d_in[8];
    const float* W_l1 = (const float*)d_in[9];
    const float* b_l1 = (const float*)d_in[10];
    const float* W_r1 = (const float*)d_in[11];

    char* ws = (char*)d_ws;
    size_t off = 0;
    auto alloc = [&](size_t bytes) {
        off = (off + 255) & ~(size_t)255;
        void* p = ws + off;
        off += bytes;
        return p;
    };
    int* cntcur = (int*)alloc((size_t)2 * NDT * 4);  // [cnt | cursor], one memset
    int* cnt = cntcur;
    int* cur = cntcur + NDT;
    int* rs = (int*)alloc((size_t)NDT * 4);
    int* csr = (int*)alloc((size_t)NET * 4);
    int* bsum = (int*)alloc(1024 * 4);
    int* boff = (int*)alloc(1024 * 4);
    ushort* h = (ushort*)alloc((size_t)ND0 * HID * 2);
    ushort* mean1 = (ushort*)alloc((size_t)ND1 * HID * 2);
    ushort* Bt0 = (ushort*)alloc((size_t)HID * (2 * F_IN) * 2);
    ushort* Bt1 = (ushort*)alloc((size_t)F_OUT * (2 * HID) * 2);

    hipMemsetAsync(cntcur, 0, (size_t)2 * NDT * 4, stream);

    // weight prep + CSR build (both layers combined)
    wtrans_all_k<<<512, 256, 0, stream>>>(W_l0, W_r0, W_l1, W_r1, Bt0, Bt1);
    hist_all_k<<<NET / 256, 256, 0, stream>>>(edst0, edst1, cnt);
    scan_part_k<<<NDT / 1024, 256, 0, stream>>>(cnt, rs, bsum, NDT);
    scan_part_k<<<1, 256, 0, stream>>>(bsum, boff, nullptr, NDT / 1024);
    scan_add_k<<<NDT / 256, 256, 0, stream>>>(rs, boff, NDT);
    scatter_all_k<<<NET / 256, 256, 0, stream>>>(esrc0, edst0, esrc1, edst1, n_id,
                                                 rs, cur, csr);

    // ---------------- Layer 1 (fused agg + gather + GEMM; x3 diagnostic) ----
    fused1_k<<<ND0 / 128, 512, 0, stream>>>(x_all, csr, rs, cnt, n_id, Bt0, b_l0, h);

    // ---------------- Layer 2 ----------------
    agg_k<HID><<<ND1, 128, 0, stream>>>(h, csr, rs, cnt, ND0, mean1);
    mgemm_k<64, HID, F_OUT, false, false>
        <<<dim3(ND1 / 64, F_OUT / 64), 256, 0, stream>>>(mean1, h, Bt1, b_l1,
                                                         (float*)d_out, ND1);
}

// Round 8
// 406.916 us; speedup vs baseline: 25.1231x; 1.4587x over previous
//
#include <hip/hip_runtime.h>

// Problem constants (from setup_inputs)
#define ND0 90112
#define ND1 8192
#define NDT (ND0 + ND1)         // 98304 combined dst space
#define NE0 1351680
#define NE1 81920
#define NET (NE0 + NE1)
#define F_IN 128
#define HID 256
#define F_OUT 128

typedef __attribute__((ext_vector_type(8))) short short8;
typedef __attribute__((ext_vector_type(4))) float f32x4;

__device__ inline ushort f2bf(float f) {
    unsigned u = __float_as_uint(f);
    return (ushort)((u + 0x7fffu + ((u >> 16) & 1u)) >> 16);
}
__device__ inline float bf2f(ushort h) {
    return __uint_as_float(((unsigned)h) << 16);
}

// ------------------------------------------------------------------
// Combined CSR build over [layer0 dsts | layer1 dsts]
// ------------------------------------------------------------------
__global__ void hist_all_k(const int* __restrict__ edst0, const int* __restrict__ edst1,
                           int* __restrict__ cnt) {
    int e = blockIdx.x * 256 + threadIdx.x;
    if (e < NE0)
        atomicAdd(&cnt[edst0[e]], 1);
    else if (e < NET)
        atomicAdd(&cnt[ND0 + edst1[e - NE0]], 1);
}

// 1024-elem chunks: per-chunk exclusive scan + chunk totals
__global__ void scan_part_k(const int* __restrict__ in, int* __restrict__ out,
                            int* __restrict__ bsum, int n) {
    __shared__ int sh[256];
    int base = blockIdx.x * 1024;
    int t = threadIdx.x;
    int v[4];
    int s = 0;
#pragma unroll
    for (int i = 0; i < 4; ++i) {
        int idx = base + t * 4 + i;
        v[i] = (idx < n) ? in[idx] : 0;
        s += v[i];
    }
    sh[t] = s;
    __syncthreads();
    for (int off = 1; off < 256; off <<= 1) {
        int x = (t >= off) ? sh[t - off] : 0;
        __syncthreads();
        sh[t] += x;
        __syncthreads();
    }
    int excl = (t == 0) ? 0 : sh[t - 1];
    if (t == 255 && bsum) bsum[blockIdx.x] = sh[255];
#pragma unroll
    for (int i = 0; i < 4; ++i) {
        int idx = base + t * 4 + i;
        if (idx < n) out[idx] = excl;
        excl += v[i];
    }
}

__global__ void scan_add_k(int* __restrict__ out, const int* __restrict__ boff, int n) {
    int i = blockIdx.x * 256 + threadIdx.x;
    if (i < n) out[i] += boff[i >> 10];
}

// scatter both layers; layer0 src pre-mapped through n_id
__global__ void scatter_all_k(const int* __restrict__ esrc0, const int* __restrict__ edst0,
                              const int* __restrict__ esrc1, const int* __restrict__ edst1,
                              const int* __restrict__ nid, const int* __restrict__ rstart,
                              int* __restrict__ cursor, int* __restrict__ csr) {
    int e = blockIdx.x * 256 + threadIdx.x;
    if (e >= NET) return;
    int d, s;
    if (e < NE0) {
        d = edst0[e];
        s = nid[esrc0[e]];
    } else {
        int e1 = e - NE0;
        d = ND0 + edst1[e1];
        s = esrc1[e1];
    }
    int pos = rstart[d] + atomicAdd(&cursor[d], 1);
    csr[pos] = s;
}

// ------------------------------------------------------------------
// Merged weight transpose+convert for both layers
// ------------------------------------------------------------------
__global__ void wtrans_all_k(const float* __restrict__ Wl0, const float* __restrict__ Wr0,
                             const float* __restrict__ Wl1, const float* __restrict__ Wr1,
                             ushort* __restrict__ Bt0, ushort* __restrict__ Bt1) {
    int idx = blockIdx.x * 256 + threadIdx.x;
    constexpr int N0 = HID * 2 * F_IN;  // 65536
    if (idx < N0) {
        int K2 = 2 * F_IN;
        int n = idx / K2, k = idx - n * K2;
        float v = (k < F_IN) ? Wl0[(size_t)k * HID + n] : Wr0[(size_t)(k - F_IN) * HID + n];
        Bt0[idx] = f2bf(v);
    } else {
        int j = idx - N0;  // F_OUT * 2 * HID = 65536
        int K2 = 2 * HID;
        int n = j / K2, k = j - n * K2;
        float v = (k < HID) ? Wl1[(size_t)k * F_OUT + n] : Wr1[(size_t)(k - HID) * F_OUT + n];
        Bt1[j] = f2bf(v);
    }
}

// ------------------------------------------------------------------
// FUSED layer-1: aggregate (mean) + x_dst gather -> LDS A-tile -> MFMA GEMM
//   h[128 rows][256] = relu([mean | x_dst] @ Bt0^T + bias)
// 704 blocks x 512 threads (8 waves). LDS: As 128x264 bf16 (67.6 KB) only.
// B fragments come straight from global (Bt0 is 128 KB, L2-resident) so the
// GEMM phase has NO barriers; single barrier between phase 1 and phase 2.
// Phase 1b: 4 passes of 32 rows; 4 edge-slots x 4 col-chunks per row,
// 2 edges in flight per slot (16 independent float4 loads outstanding).
// ------------------------------------------------------------------
__global__ __launch_bounds__(512, 4) void fused1_k(
    const float* __restrict__ X, const int* __restrict__ csr,
    const int* __restrict__ rstart, const int* __restrict__ cnt,
    const int* __restrict__ nid, const ushort* __restrict__ Bt,
    const float* __restrict__ bias, ushort* __restrict__ C) {
    __shared__ ushort As[128][264];  // [row][mean(0..127) | xdst(128..255)], +8 pad
    __shared__ int s_beg[128], s_num[128];

    int t = threadIdx.x;
    int row0 = blockIdx.x * 128;

    if (t < 128) {
        s_beg[t] = rstart[row0 + t];
        s_num[t] = cnt[row0 + t];
    }
    __syncthreads();

    // ---------- phase 1a: x_dst gather ----------
    {
        int row = t >> 2, q = t & 3;
        int gr = nid[row0 + row];
        const float* gp = &X[(size_t)gr * F_IN + q * 32];
#pragma unroll
        for (int i = 0; i < 4; ++i) {
            float4 v0 = *(const float4*)(gp + i * 8);
            float4 v1 = *(const float4*)(gp + i * 8 + 4);
            short8 o;
            o[0] = (short)f2bf(v0.x); o[1] = (short)f2bf(v0.y);
            o[2] = (short)f2bf(v0.z); o[3] = (short)f2bf(v0.w);
            o[4] = (short)f2bf(v1.x); o[5] = (short)f2bf(v1.y);
            o[6] = (short)f2bf(v1.z); o[7] = (short)f2bf(v1.w);
            *(short8*)&As[row][F_IN + q * 32 + i * 8] = o;
        }
    }

    // ---------- phase 1b: edge aggregation, 4 passes of 32 rows ----------
    {
        int q = t & 3;             // col chunk (32 floats)
        int slot = (t >> 2) & 3;   // edge slot (lane bits 2..3)
        int rloc = t >> 4;         // row within pass [0,32)
#pragma unroll 1
        for (int pass = 0; pass < 4; ++pass) {
            int row = pass * 32 + rloc;
            int beg = s_beg[row], num = s_num[row];
            float acc[32] = {};
#pragma unroll 1
            for (int e = slot; e < num; e += 8) {
                int e1 = e + 4;
                int r0 = csr[beg + e];
                const float* p0 = &X[(size_t)r0 * F_IN + q * 32];
                if (e1 < num) {
                    int r1 = csr[beg + e1];
                    const float* p1 = &X[(size_t)r1 * F_IN + q * 32];
                    float4 v0[8], v1[8];
#pragma unroll
                    for (int i = 0; i < 8; ++i) v0[i] = *(const float4*)(p0 + i * 4);
#pragma unroll
                    for (int i = 0; i < 8; ++i) v1[i] = *(const float4*)(p1 + i * 4);
#pragma unroll
                    for (int i = 0; i < 8; ++i) {
                        acc[i * 4 + 0] += v0[i].x + v1[i].x;
                        acc[i * 4 + 1] += v0[i].y + v1[i].y;
                        acc[i * 4 + 2] += v0[i].z + v1[i].z;
                        acc[i * 4 + 3] += v0[i].w + v1[i].w;
                    }
                } else {
#pragma unroll
                    for (int i = 0; i < 8; ++i) {
                        float4 v = *(const float4*)(p0 + i * 4);
                        acc[i * 4 + 0] += v.x;
                        acc[i * 4 + 1] += v.y;
                        acc[i * 4 + 2] += v.z;
                        acc[i * 4 + 3] += v.w;
                    }
                }
            }
            // combine the 4 slots (lane bits 2..3) via butterfly
#pragma unroll
            for (int i = 0; i < 32; ++i) {
                acc[i] += __shfl_xor(acc[i], 4);
                acc[i] += __shfl_xor(acc[i], 8);
            }
            if (slot == 0) {
                float inv = 1.f / (float)((num > 0) ? num : 1);
#pragma unroll
                for (int i = 0; i < 4; ++i) {
                    short8 o;
#pragma unroll
                    for (int j = 0; j < 8; ++j) o[j] = (short)f2bf(acc[i * 8 + j] * inv);
                    *(short8*)&As[row][q * 32 + i * 8] = o;
                }
            }
        }
    }

    __syncthreads();  // As complete; no further barriers

    // ---------- phase 2: GEMM (B direct from global) ----------
    int lane = t & 63;
    int w = t >> 6;
    int wm = w >> 2, wn2 = w & 3;  // 2(m) x 4(n) wave grid; wave tile 64m x 16n
    int lr = lane & 15, lj = lane >> 4;

#pragma unroll 1
    for (int nt = 0; nt < 4; ++nt) {
        f32x4 acc2[4] = {};
        const ushort* bp = &Bt[(size_t)(nt * 64 + wn2 * 16 + lr) * 256 + lj * 8];
#pragma unroll
        for (int k = 0; k < 256; k += 32) {
            short8 bf = *(const short8*)(bp + k);
#pragma unroll
            for (int mi = 0; mi < 4; ++mi) {
                short8 af = *(const short8*)&As[wm * 64 + mi * 16 + lr][k + lj * 8];
                acc2[mi] = __builtin_amdgcn_mfma_f32_16x16x32_bf16(af, bf, acc2[mi], 0, 0, 0);
            }
        }
        int c = nt * 64 + wn2 * 16 + lr;
        float bi = bias[c];
#pragma unroll
        for (int mi = 0; mi < 4; ++mi) {
#pragma unroll
            for (int j = 0; j < 4; ++j) {
                int r = row0 + wm * 64 + mi * 16 + lj * 4 + j;
                float v = acc2[mi][j] + bi;
                v = fmaxf(v, 0.f);
                C[(size_t)r * HID + c] = f2bf(v);
            }
        }
    }
}

// ------------------------------------------------------------------
// Mean aggregation (layer 2), vectorized 16B/lane, bf16 in.
// ------------------------------------------------------------------
template <int F>
__global__ __launch_bounds__(128) void agg_k(
    const ushort* __restrict__ Xh, const int* __restrict__ csr,
    const int* __restrict__ rstart, const int* __restrict__ cnt, int dofs,
    ushort* __restrict__ mean) {
    __shared__ float sh[128][8];
    int d = blockIdx.x;
    int t = threadIdx.x;
    int cg = t & 31, slot = t >> 5;
    int beg = rstart[dofs + d];
    int num = cnt[dofs + d];
    float acc[8] = {};
    for (int e = 0; e < num; e += 8) {
        int i0 = e + slot, i1 = e + 4 + slot;
        bool v0 = i0 < num, v1 = i1 < num;
        int r0 = v0 ? csr[beg + i0] : 0;
        int r1 = v1 ? csr[beg + i1] : 0;
        if (v0) {
            short8 x = *(const short8*)&Xh[(size_t)r0 * F + cg * 8];
#pragma unroll
            for (int i = 0; i < 8; ++i) acc[i] += bf2f((ushort)x[i]);
        }
        if (v1) {
            short8 x = *(const short8*)&Xh[(size_t)r1 * F + cg * 8];
#pragma unroll
            for (int i = 0; i < 8; ++i) acc[i] += bf2f((ushort)x[i]);
        }
    }
#pragma unroll
    for (int i = 0; i < 8; ++i) sh[t][i] = acc[i];
    __syncthreads();
    if (t < 32) {
        float inv = 1.f / (float)((num > 0) ? num : 1);
        short8 ov;
#pragma unroll
        for (int i = 0; i < 8; ++i) {
            float s = sh[t][i] + sh[t + 32][i] + sh[t + 64][i] + sh[t + 96][i];
            ov[i] = (short)f2bf(s * inv);
        }
        *(short8*)&mean[(size_t)d * F + t * 8] = ov;
    }
}

// ------------------------------------------------------------------
// bf16 MFMA concat-K GEMM (layer 2): C = [A0 | A1] @ Bt^T + bias
// ------------------------------------------------------------------
template <int BM, int KHALF, int NCOLS, bool RELU, bool OUT_BF16>
__global__ __launch_bounds__(256) void mgemm_k(
    const ushort* __restrict__ A0, const ushort* __restrict__ A1,
    const ushort* __restrict__ Bt, const float* __restrict__ bias,
    void* __restrict__ Cv, int M) {
    constexpr int MI = BM / 32;
    constexpr int TPR = 256 / BM;
    constexpr int AV = 64 / TPR / 8;
    __shared__ ushort As[BM][72];
    __shared__ ushort Bs[64][72];

    int t = threadIdx.x;
    int row0 = blockIdx.x * BM;
    int col0 = blockIdx.y * 64;
    int lane = t & 63;
    int w = t >> 6, wm = w >> 1, wn = w & 1;
    int lr = lane & 15;
    int lk = (lane >> 4) * 8;

    int ar = t / TPR, ac = (t % TPR) * (64 / TPR);
    int bn = t >> 2, bc = (t & 3) * 16;

    f32x4 acc[MI][2] = {};

    for (int k0 = 0; k0 < 2 * KHALF; k0 += 64) {
        const ushort* Asrc = (k0 < KHALF) ? A0 : A1;
        int kof = (k0 < KHALF) ? k0 : (k0 - KHALF);
        const ushort* ap = &Asrc[(size_t)(row0 + ar) * KHALF + kof + ac];
        const ushort* bp = &Bt[(size_t)(col0 + bn) * (2 * KHALF) + k0 + bc];
        short8 av[AV];
#pragma unroll
        for (int i = 0; i < AV; ++i) av[i] = *(const short8*)(ap + 8 * i);
        short8 bv0 = *(const short8*)(bp);
        short8 bv1 = *(const short8*)(bp + 8);
        __syncthreads();
#pragma unroll
        for (int i = 0; i < AV; ++i) *(short8*)&As[ar][ac + 8 * i] = av[i];
        *(short8*)&Bs[bn][bc + 0] = bv0;
        *(short8*)&Bs[bn][bc + 8] = bv1;
        __syncthreads();
#pragma unroll
        for (int ks = 0; ks < 64; ks += 32) {
            short8 bf0 = *(const short8*)&Bs[wn * 32 + lr][ks + lk];
            short8 bf1 = *(const short8*)&Bs[wn * 32 + 16 + lr][ks + lk];
#pragma unroll
            for (int mi = 0; mi < MI; ++mi) {
                short8 af = *(const short8*)&As[wm * (BM / 2) + mi * 16 + lr][ks + lk];
                acc[mi][0] = __builtin_amdgcn_mfma_f32_16x16x32_bf16(af, bf0, acc[mi][0], 0, 0, 0);
                acc[mi][1] = __builtin_amdgcn_mfma_f32_16x16x32_bf16(af, bf1, acc[mi][1], 0, 0, 0);
            }
        }
    }

    int orow = row0 + wm * (BM / 2);
    int ocol = col0 + wn * 32;
#pragma unroll
    for (int mi = 0; mi < MI; ++mi) {
#pragma unroll
        for (int ni = 0; ni < 2; ++ni) {
            int c = ocol + ni * 16 + lr;
            float bi = bias[c];
#pragma unroll
            for (int j = 0; j < 4; ++j) {
                int r = orow + mi * 16 + (lane >> 4) * 4 + j;
                float v = acc[mi][ni][j] + bi;
                if (RELU) v = fmaxf(v, 0.f);
                if (OUT_BF16)
                    ((ushort*)Cv)[(size_t)r * NCOLS + c] = f2bf(v);
                else
                    ((float*)Cv)[(size_t)r * NCOLS + c] = v;
            }
        }
    }
}

// ------------------------------------------------------------------
extern "C" void kernel_launch(void* const* d_in, const int* in_sizes, int n_in,
                              void* d_out, int out_size, void* d_ws, size_t ws_size,
                              hipStream_t stream) {
    const float* x_all = (const float*)d_in[0];
    const int* n_id = (const int*)d_in[1];
    const int* esrc0 = (const int*)d_in[2];
    const int* edst0 = (const int*)d_in[3];
    const int* esrc1 = (const int*)d_in[4];
    const int* edst1 = (const int*)d_in[5];
    const float* W_l0 = (const float*)d_in[6];
    const float* b_l0 = (const float*)d_in[7];
    const float* W_r0 = (const float*)d_in[8];
    const float* W_l1 = (const float*)d_in[9];
    const float* b_l1 = (const float*)d_in[10];
    const float* W_r1 = (const float*)d_in[11];

    char* ws = (char*)d_ws;
    size_t off = 0;
    auto alloc = [&](size_t bytes) {
        off = (off + 255) & ~(size_t)255;
        void* p = ws + off;
        off += bytes;
        return p;
    };
    int* cntcur = (int*)alloc((size_t)2 * NDT * 4);  // [cnt | cursor], one memset
    int* cnt = cntcur;
    int* cur = cntcur + NDT;
    int* rs = (int*)alloc((size_t)NDT * 4);
    int* csr = (int*)alloc((size_t)NET * 4);
    int* bsum = (int*)alloc(1024 * 4);
    int* boff = (int*)alloc(1024 * 4);
    ushort* h = (ushort*)alloc((size_t)ND0 * HID * 2);
    ushort* mean1 = (ushort*)alloc((size_t)ND1 * HID * 2);
    ushort* Bt0 = (ushort*)alloc((size_t)HID * (2 * F_IN) * 2);
    ushort* Bt1 = (ushort*)alloc((size_t)F_OUT * (2 * HID) * 2);

    hipMemsetAsync(cntcur, 0, (size_t)2 * NDT * 4, stream);

    // weight prep + CSR build (both layers combined)
    wtrans_all_k<<<512, 256, 0, stream>>>(W_l0, W_r0, W_l1, W_r1, Bt0, Bt1);
    hist_all_k<<<NET / 256, 256, 0, stream>>>(edst0, edst1, cnt);
    scan_part_k<<<NDT / 1024, 256, 0, stream>>>(cnt, rs, bsum, NDT);
    scan_part_k<<<1, 256, 0, stream>>>(bsum, boff, nullptr, NDT / 1024);
    scan_add_k<<<NDT / 256, 256, 0, stream>>>(rs, boff, NDT);
    scatter_all_k<<<NET / 256, 256, 0, stream>>>(esrc0, edst0, esrc1, edst1, n_id,
                                                 rs, cur, csr);

    // ---------------- Layer 1 (fused agg + gather + GEMM) ----------------
    fused1_k<<<ND0 / 128, 512, 0, stream>>>(x_all, csr, rs, cnt, n_id, Bt0, b_l0, h);

    // ---------------- Layer 2 ----------------
    agg_k<HID><<<ND1, 128, 0, stream>>>(h, csr, rs, cnt, ND0, mean1);
    mgemm_k<64, HID, F_OUT, false, false>
        <<<dim3(ND1 / 64, F_OUT / 64), 256, 0, stream>>>(mean1, h, Bt1, b_l1,
                                                         (float*)d_out, ND1);
}

// Round 9
// 314.666 us; speedup vs baseline: 32.4884x; 1.2932x over previous
//
#include <hip/hip_runtime.h>

// Problem constants (from setup_inputs)
#define ND0 90112
#define ND1 8192
#define NDT (ND0 + ND1)         // 98304 combined dst space
#define NE0 1351680
#define NE1 81920
#define NET (NE0 + NE1)
#define F_IN 128
#define HID 256
#define F_OUT 128

typedef __attribute__((ext_vector_type(8))) short short8;
typedef __attribute__((ext_vector_type(4))) float f32x4;

__device__ inline ushort f2bf(float f) {
    unsigned u = __float_as_uint(f);
    return (ushort)((u + 0x7fffu + ((u >> 16) & 1u)) >> 16);
}
__device__ inline float bf2f(ushort h) {
    return __uint_as_float(((unsigned)h) << 16);
}

// ------------------------------------------------------------------
// Combined CSR build over [layer0 dsts | layer1 dsts]
// ------------------------------------------------------------------
__global__ void hist_all_k(const int* __restrict__ edst0, const int* __restrict__ edst1,
                           int* __restrict__ cnt) {
    int e = blockIdx.x * 256 + threadIdx.x;
    if (e < NE0)
        atomicAdd(&cnt[edst0[e]], 1);
    else if (e < NET)
        atomicAdd(&cnt[ND0 + edst1[e - NE0]], 1);
}

// 1024-elem chunks: per-chunk exclusive scan + chunk totals
__global__ void scan_part_k(const int* __restrict__ in, int* __restrict__ out,
                            int* __restrict__ bsum, int n) {
    __shared__ int sh[256];
    int base = blockIdx.x * 1024;
    int t = threadIdx.x;
    int v[4];
    int s = 0;
#pragma unroll
    for (int i = 0; i < 4; ++i) {
        int idx = base + t * 4 + i;
        v[i] = (idx < n) ? in[idx] : 0;
        s += v[i];
    }
    sh[t] = s;
    __syncthreads();
    for (int off = 1; off < 256; off <<= 1) {
        int x = (t >= off) ? sh[t - off] : 0;
        __syncthreads();
        sh[t] += x;
        __syncthreads();
    }
    int excl = (t == 0) ? 0 : sh[t - 1];
    if (t == 255 && bsum) bsum[blockIdx.x] = sh[255];
#pragma unroll
    for (int i = 0; i < 4; ++i) {
        int idx = base + t * 4 + i;
        if (idx < n) out[idx] = excl;
        excl += v[i];
    }
}

__global__ void scan_add_k(int* __restrict__ out, const int* __restrict__ boff, int n) {
    int i = blockIdx.x * 256 + threadIdx.x;
    if (i < n) out[i] += boff[i >> 10];
}

// scatter both layers; layer0 src pre-mapped through n_id
__global__ void scatter_all_k(const int* __restrict__ esrc0, const int* __restrict__ edst0,
                              const int* __restrict__ esrc1, const int* __restrict__ edst1,
                              const int* __restrict__ nid, const int* __restrict__ rstart,
                              int* __restrict__ cursor, int* __restrict__ csr) {
    int e = blockIdx.x * 256 + threadIdx.x;
    if (e >= NET) return;
    int d, s;
    if (e < NE0) {
        d = edst0[e];
        s = nid[esrc0[e]];
    } else {
        int e1 = e - NE0;
        d = ND0 + edst1[e1];
        s = esrc1[e1];
    }
    int pos = rstart[d] + atomicAdd(&cursor[d], 1);
    csr[pos] = s;
}

// ------------------------------------------------------------------
// Merged weight transpose+convert for both layers
// ------------------------------------------------------------------
__global__ void wtrans_all_k(const float* __restrict__ Wl0, const float* __restrict__ Wr0,
                             const float* __restrict__ Wl1, const float* __restrict__ Wr1,
                             ushort* __restrict__ Bt0, ushort* __restrict__ Bt1) {
    int idx = blockIdx.x * 256 + threadIdx.x;
    constexpr int N0 = HID * 2 * F_IN;  // 65536
    if (idx < N0) {
        int K2 = 2 * F_IN;
        int n = idx / K2, k = idx - n * K2;
        float v = (k < F_IN) ? Wl0[(size_t)k * HID + n] : Wr0[(size_t)(k - F_IN) * HID + n];
        Bt0[idx] = f2bf(v);
    } else {
        int j = idx - N0;  // F_OUT * 2 * HID = 65536
        int K2 = 2 * HID;
        int n = j / K2, k = j - n * K2;
        float v = (k < HID) ? Wl1[(size_t)k * F_OUT + n] : Wr1[(size_t)(k - HID) * F_OUT + n];
        Bt1[j] = f2bf(v);
    }
}

// ------------------------------------------------------------------
// FUSED layer-1: aggregate (mean) + x_dst gather -> LDS A-tile -> MFMA GEMM
//   h[64 rows][256] = relu([mean | x_dst] @ Bt0^T + bias)
// BM=64: 1408 blocks x 512 threads (8 waves). LDS ~43 KB -> 3 blocks/CU
// (24 waves/CU vs 16 at BM=128 — occupancy was the R7-measured limiter).
// Phase 1b: 2 passes of 32 rows; 4 edge-slots x 4 col-chunks per row,
// slot partials combined via __shfl_xor (slots = lane bits 2..3).
// ------------------------------------------------------------------
__global__ __launch_bounds__(512, 4) void fused1_k(
    const float* __restrict__ X, const int* __restrict__ csr,
    const int* __restrict__ rstart, const int* __restrict__ cnt,
    const int* __restrict__ nid, const ushort* __restrict__ Bt,
    const float* __restrict__ bias, ushort* __restrict__ C) {
    __shared__ ushort As[64][264];  // [row][mean(0..127) | xdst(128..255)], +8 pad
    __shared__ ushort Bs[64][72];
    __shared__ int s_beg[64], s_num[64];

    int t = threadIdx.x;
    int row0 = blockIdx.x * 64;

    if (t < 64) {
        s_beg[t] = rstart[row0 + t];
        s_num[t] = cnt[row0 + t];
    }
    __syncthreads();

    // ---------- phase 1a: x_dst gather (8 threads/row, 16 cols each) ----------
    {
        int row = t >> 3, q = t & 7;
        int gr = nid[row0 + row];
        const float* gp = &X[(size_t)gr * F_IN + q * 16];
#pragma unroll
        for (int i = 0; i < 2; ++i) {
            float4 v0 = *(const float4*)(gp + i * 8);
            float4 v1 = *(const float4*)(gp + i * 8 + 4);
            short8 o;
            o[0] = (short)f2bf(v0.x); o[1] = (short)f2bf(v0.y);
            o[2] = (short)f2bf(v0.z); o[3] = (short)f2bf(v0.w);
            o[4] = (short)f2bf(v1.x); o[5] = (short)f2bf(v1.y);
            o[6] = (short)f2bf(v1.z); o[7] = (short)f2bf(v1.w);
            *(short8*)&As[row][F_IN + q * 16 + i * 8] = o;
        }
    }

    // ---------- phase 1b: edge aggregation, 2 passes of 32 rows ----------
    {
        int q = t & 3;             // col chunk (32 floats)
        int slot = (t >> 2) & 3;   // edge slot (lane bits 2..3)
        int rloc = t >> 4;         // row within pass [0,32)
#pragma unroll 1
        for (int pass = 0; pass < 2; ++pass) {
            int row = pass * 32 + rloc;
            int beg = s_beg[row], num = s_num[row];
            float acc[32] = {};
#pragma unroll 1
            for (int e = slot; e < num; e += 4) {
                int r = csr[beg + e];
                const float* rp = &X[(size_t)r * F_IN + q * 32];
#pragma unroll
                for (int i = 0; i < 8; ++i) {
                    float4 v = *(const float4*)(rp + i * 4);
                    acc[i * 4 + 0] += v.x;
                    acc[i * 4 + 1] += v.y;
                    acc[i * 4 + 2] += v.z;
                    acc[i * 4 + 3] += v.w;
                }
            }
            // combine the 4 slots (lane bits 2..3) via butterfly
#pragma unroll
            for (int i = 0; i < 32; ++i) {
                acc[i] += __shfl_xor(acc[i], 4);
                acc[i] += __shfl_xor(acc[i], 8);
            }
            if (slot == 0) {
                float inv = 1.f / (float)((num > 0) ? num : 1);
#pragma unroll
                for (int i = 0; i < 4; ++i) {
                    short8 o;
#pragma unroll
                    for (int j = 0; j < 8; ++j) o[j] = (short)f2bf(acc[i * 8 + j] * inv);
                    *(short8*)&As[row][q * 32 + i * 8] = o;
                }
            }
        }
    }

    // ---------- phase 2: GEMM (Bs-staged, wave tile 32m x 16n) ----------
    int lane = t & 63;
    int w = t >> 6;
    int wm = w >> 2, wn2 = w & 3;  // 2(m) x 4(n) wave grid
    int lr = lane & 15, lj = lane >> 4;
    int bn = t >> 3, bk = (t & 7) * 8;  // B stage map: 64 n-rows x 64 k

    for (int nt = 0; nt < 4; ++nt) {
        f32x4 acc2[2] = {};
        for (int k0 = 0; k0 < 256; k0 += 64) {
            short8 bv = *(const short8*)&Bt[(size_t)(nt * 64 + bn) * 256 + k0 + bk];
            __syncthreads();  // As writes done (1st iter); prior Bs reads done
            *(short8*)&Bs[bn][bk] = bv;
            __syncthreads();
#pragma unroll
            for (int ks = 0; ks < 64; ks += 32) {
                short8 bf = *(const short8*)&Bs[wn2 * 16 + lr][ks + lj * 8];
#pragma unroll
                for (int mi = 0; mi < 2; ++mi) {
                    short8 af = *(const short8*)&As[wm * 32 + mi * 16 + lr][k0 + ks + lj * 8];
                    acc2[mi] = __builtin_amdgcn_mfma_f32_16x16x32_bf16(af, bf, acc2[mi], 0, 0, 0);
                }
            }
        }
        int c = nt * 64 + wn2 * 16 + lr;
        float bi = bias[c];
#pragma unroll
        for (int mi = 0; mi < 2; ++mi) {
#pragma unroll
            for (int j = 0; j < 4; ++j) {
                int r = row0 + wm * 32 + mi * 16 + lj * 4 + j;
                float v = acc2[mi][j] + bi;
                v = fmaxf(v, 0.f);
                C[(size_t)r * HID + c] = f2bf(v);
            }
        }
    }
}

// ------------------------------------------------------------------
// Mean aggregation (layer 2), vectorized 16B/lane, bf16 in.
// ------------------------------------------------------------------
template <int F>
__global__ __launch_bounds__(128) void agg_k(
    const ushort* __restrict__ Xh, const int* __restrict__ csr,
    const int* __restrict__ rstart, const int* __restrict__ cnt, int dofs,
    ushort* __restrict__ mean) {
    __shared__ float sh[128][8];
    int d = blockIdx.x;
    int t = threadIdx.x;
    int cg = t & 31, slot = t >> 5;
    int beg = rstart[dofs + d];
    int num = cnt[dofs + d];
    float acc[8] = {};
    for (int e = 0; e < num; e += 8) {
        int i0 = e + slot, i1 = e + 4 + slot;
        bool v0 = i0 < num, v1 = i1 < num;
        int r0 = v0 ? csr[beg + i0] : 0;
        int r1 = v1 ? csr[beg + i1] : 0;
        if (v0) {
            short8 x = *(const short8*)&Xh[(size_t)r0 * F + cg * 8];
#pragma unroll
            for (int i = 0; i < 8; ++i) acc[i] += bf2f((ushort)x[i]);
        }
        if (v1) {
            short8 x = *(const short8*)&Xh[(size_t)r1 * F + cg * 8];
#pragma unroll
            for (int i = 0; i < 8; ++i) acc[i] += bf2f((ushort)x[i]);
        }
    }
#pragma unroll
    for (int i = 0; i < 8; ++i) sh[t][i] = acc[i];
    __syncthreads();
    if (t < 32) {
        float inv = 1.f / (float)((num > 0) ? num : 1);
        short8 ov;
#pragma unroll
        for (int i = 0; i < 8; ++i) {
            float s = sh[t][i] + sh[t + 32][i] + sh[t + 64][i] + sh[t + 96][i];
            ov[i] = (short)f2bf(s * inv);
        }
        *(short8*)&mean[(size_t)d * F + t * 8] = ov;
    }
}

// ------------------------------------------------------------------
// bf16 MFMA concat-K GEMM (layer 2): C = [A0 | A1] @ Bt^T + bias
// ------------------------------------------------------------------
template <int BM, int KHALF, int NCOLS, bool RELU, bool OUT_BF16>
__global__ __launch_bounds__(256) void mgemm_k(
    const ushort* __restrict__ A0, const ushort* __restrict__ A1,
    const ushort* __restrict__ Bt, const float* __restrict__ bias,
    void* __restrict__ Cv, int M) {
    constexpr int MI = BM / 32;
    constexpr int TPR = 256 / BM;
    constexpr int AV = 64 / TPR / 8;
    __shared__ ushort As[BM][72];
    __shared__ ushort Bs[64][72];

    int t = threadIdx.x;
    int row0 = blockIdx.x * BM;
    int col0 = blockIdx.y * 64;
    int lane = t & 63;
    int w = t >> 6, wm = w >> 1, wn = w & 1;
    int lr = lane & 15;
    int lk = (lane >> 4) * 8;

    int ar = t / TPR, ac = (t % TPR) * (64 / TPR);
    int bn = t >> 2, bc = (t & 3) * 16;

    f32x4 acc[MI][2] = {};

    for (int k0 = 0; k0 < 2 * KHALF; k0 += 64) {
        const ushort* Asrc = (k0 < KHALF) ? A0 : A1;
        int kof = (k0 < KHALF) ? k0 : (k0 - KHALF);
        const ushort* ap = &Asrc[(size_t)(row0 + ar) * KHALF + kof + ac];
        const ushort* bp = &Bt[(size_t)(col0 + bn) * (2 * KHALF) + k0 + bc];
        short8 av[AV];
#pragma unroll
        for (int i = 0; i < AV; ++i) av[i] = *(const short8*)(ap + 8 * i);
        short8 bv0 = *(const short8*)(bp);
        short8 bv1 = *(const short8*)(bp + 8);
        __syncthreads();
#pragma unroll
        for (int i = 0; i < AV; ++i) *(short8*)&As[ar][ac + 8 * i] = av[i];
        *(short8*)&Bs[bn][bc + 0] = bv0;
        *(short8*)&Bs[bn][bc + 8] = bv1;
        __syncthreads();
#pragma unroll
        for (int ks = 0; ks < 64; ks += 32) {
            short8 bf0 = *(const short8*)&Bs[wn * 32 + lr][ks + lk];
            short8 bf1 = *(const short8*)&Bs[wn * 32 + 16 + lr][ks + lk];
#pragma unroll
            for (int mi = 0; mi < MI; ++mi) {
                short8 af = *(const short8*)&As[wm * (BM / 2) + mi * 16 + lr][ks + lk];
                acc[mi][0] = __builtin_amdgcn_mfma_f32_16x16x32_bf16(af, bf0, acc[mi][0], 0, 0, 0);
                acc[mi][1] = __builtin_amdgcn_mfma_f32_16x16x32_bf16(af, bf1, acc[mi][1], 0, 0, 0);
            }
        }
    }

    int orow = row0 + wm * (BM / 2);
    int ocol = col0 + wn * 32;
#pragma unroll
    for (int mi = 0; mi < MI; ++mi) {
#pragma unroll
        for (int ni = 0; ni < 2; ++ni) {
            int c = ocol + ni * 16 + lr;
            float bi = bias[c];
#pragma unroll
            for (int j = 0; j < 4; ++j) {
                int r = orow + mi * 16 + (lane >> 4) * 4 + j;
                float v = acc[mi][ni][j] + bi;
                if (RELU) v = fmaxf(v, 0.f);
                if (OUT_BF16)
                    ((ushort*)Cv)[(size_t)r * NCOLS + c] = f2bf(v);
                else
                    ((float*)Cv)[(size_t)r * NCOLS + c] = v;
            }
        }
    }
}

// ------------------------------------------------------------------
extern "C" void kernel_launch(void* const* d_in, const int* in_sizes, int n_in,
                              void* d_out, int out_size, void* d_ws, size_t ws_size,
                              hipStream_t stream) {
    const float* x_all = (const float*)d_in[0];
    const int* n_id = (const int*)d_in[1];
    const int* esrc0 = (const int*)d_in[2];
    const int* edst0 = (const int*)d_in[3];
    const int* esrc1 = (const int*)d_in[4];
    const int* edst1 = (const int*)d_in[5];
    const float* W_l0 = (const float*)d_in[6];
    const float* b_l0 = (const float*)d_in[7];
    const float* W_r0 = (const float*)d_in[8];
    const float* W_l1 = (const float*)d_in[9];
    const float* b_l1 = (const float*)d_in[10];
    const float* W_r1 = (const float*)d_in[11];

    char* ws = (char*)d_ws;
    size_t off = 0;
    auto alloc = [&](size_t bytes) {
        off = (off + 255) & ~(size_t)255;
        void* p = ws + off;
        off += bytes;
        return p;
    };
    int* cntcur = (int*)alloc((size_t)2 * NDT * 4);  // [cnt | cursor], one memset
    int* cnt = cntcur;
    int* cur = cntcur + NDT;
    int* rs = (int*)alloc((size_t)NDT * 4);
    int* csr = (int*)alloc((size_t)NET * 4);
    int* bsum = (int*)alloc(1024 * 4);
    int* boff = (int*)alloc(1024 * 4);
    ushort* h = (ushort*)alloc((size_t)ND0 * HID * 2);
    ushort* mean1 = (ushort*)alloc((size_t)ND1 * HID * 2);
    ushort* Bt0 = (ushort*)alloc((size_t)HID * (2 * F_IN) * 2);
    ushort* Bt1 = (ushort*)alloc((size_t)F_OUT * (2 * HID) * 2);

    hipMemsetAsync(cntcur, 0, (size_t)2 * NDT * 4, stream);

    // weight prep + CSR build (both layers combined)
    wtrans_all_k<<<512, 256, 0, stream>>>(W_l0, W_r0, W_l1, W_r1, Bt0, Bt1);
    hist_all_k<<<NET / 256, 256, 0, stream>>>(edst0, edst1, cnt);
    scan_part_k<<<NDT / 1024, 256, 0, stream>>>(cnt, rs, bsum, NDT);
    scan_part_k<<<1, 256, 0, stream>>>(bsum, boff, nullptr, NDT / 1024);
    scan_add_k<<<NDT / 256, 256, 0, stream>>>(rs, boff, NDT);
    scatter_all_k<<<NET / 256, 256, 0, stream>>>(esrc0, edst0, esrc1, edst1, n_id,
                                                 rs, cur, csr);

    // ---------------- Layer 1 (fused agg + gather + GEMM) ----------------
    fused1_k<<<ND0 / 64, 512, 0, stream>>>(x_all, csr, rs, cnt, n_id, Bt0, b_l0, h);

    // ---------------- Layer 2 ----------------
    agg_k<HID><<<ND1, 128, 0, stream>>>(h, csr, rs, cnt, ND0, mean1);
    mgemm_k<64, HID, F_OUT, false, false>
        <<<dim3(ND1 / 64, F_OUT / 64), 256, 0, stream>>>(mean1, h, Bt1, b_l1,
                                                         (float*)d_out, ND1);
}

// Round 10
// 296.868 us; speedup vs baseline: 34.4362x; 1.0600x over previous
//
#include <hip/hip_runtime.h>

// Problem constants (from setup_inputs)
#define ND0 90112
#define ND1 8192
#define NDT (ND0 + ND1)         // 98304 combined dst space
#define NE0 1351680
#define NE1 81920
#define NET (NE0 + NE1)
#define F_IN 128
#define HID 256
#define F_OUT 128

typedef __attribute__((ext_vector_type(8))) short short8;
typedef __attribute__((ext_vector_type(4))) float f32x4;

__device__ inline ushort f2bf(float f) {
    unsigned u = __float_as_uint(f);
    return (ushort)((u + 0x7fffu + ((u >> 16) & 1u)) >> 16);
}
__device__ inline float bf2f(ushort h) {
    return __uint_as_float(((unsigned)h) << 16);
}

// ------------------------------------------------------------------
// Combined CSR build over [layer0 dsts | layer1 dsts]
// ------------------------------------------------------------------
__global__ void hist_all_k(const int* __restrict__ edst0, const int* __restrict__ edst1,
                           int* __restrict__ cnt) {
    int e = blockIdx.x * 256 + threadIdx.x;
    if (e < NE0)
        atomicAdd(&cnt[edst0[e]], 1);
    else if (e < NET)
        atomicAdd(&cnt[ND0 + edst1[e - NE0]], 1);
}

// 1024-elem chunks: per-chunk exclusive scan + chunk totals
__global__ void scan_part_k(const int* __restrict__ in, int* __restrict__ out,
                            int* __restrict__ bsum, int n) {
    __shared__ int sh[256];
    int base = blockIdx.x * 1024;
    int t = threadIdx.x;
    int v[4];
    int s = 0;
#pragma unroll
    for (int i = 0; i < 4; ++i) {
        int idx = base + t * 4 + i;
        v[i] = (idx < n) ? in[idx] : 0;
        s += v[i];
    }
    sh[t] = s;
    __syncthreads();
    for (int off = 1; off < 256; off <<= 1) {
        int x = (t >= off) ? sh[t - off] : 0;
        __syncthreads();
        sh[t] += x;
        __syncthreads();
    }
    int excl = (t == 0) ? 0 : sh[t - 1];
    if (t == 255 && bsum) bsum[blockIdx.x] = sh[255];
#pragma unroll
    for (int i = 0; i < 4; ++i) {
        int idx = base + t * 4 + i;
        if (idx < n) out[idx] = excl;
        excl += v[i];
    }
}

__global__ void scan_add_k(int* __restrict__ out, const int* __restrict__ boff, int n) {
    int i = blockIdx.x * 256 + threadIdx.x;
    if (i < n) out[i] += boff[i >> 10];
}

// scatter both layers; layer0 src pre-mapped through n_id
__global__ void scatter_all_k(const int* __restrict__ esrc0, const int* __restrict__ edst0,
                              const int* __restrict__ esrc1, const int* __restrict__ edst1,
                              const int* __restrict__ nid, const int* __restrict__ rstart,
                              int* __restrict__ cursor, int* __restrict__ csr) {
    int e = blockIdx.x * 256 + threadIdx.x;
    if (e >= NET) return;
    int d, s;
    if (e < NE0) {
        d = edst0[e];
        s = nid[esrc0[e]];
    } else {
        int e1 = e - NE0;
        d = ND0 + edst1[e1];
        s = esrc1[e1];
    }
    int pos = rstart[d] + atomicAdd(&cursor[d], 1);
    csr[pos] = s;
}

// ------------------------------------------------------------------
// Merged weight transpose+convert for both layers
// ------------------------------------------------------------------
__global__ void wtrans_all_k(const float* __restrict__ Wl0, const float* __restrict__ Wr0,
                             const float* __restrict__ Wl1, const float* __restrict__ Wr1,
                             ushort* __restrict__ Bt0, ushort* __restrict__ Bt1) {
    int idx = blockIdx.x * 256 + threadIdx.x;
    constexpr int N0 = HID * 2 * F_IN;  // 65536
    if (idx < N0) {
        int K2 = 2 * F_IN;
        int n = idx / K2, k = idx - n * K2;
        float v = (k < F_IN) ? Wl0[(size_t)k * HID + n] : Wr0[(size_t)(k - F_IN) * HID + n];
        Bt0[idx] = f2bf(v);
    } else {
        int j = idx - N0;  // F_OUT * 2 * HID = 65536
        int K2 = 2 * HID;
        int n = j / K2, k = j - n * K2;
        float v = (k < HID) ? Wl1[(size_t)k * F_OUT + n] : Wr1[(size_t)(k - HID) * F_OUT + n];
        Bt1[j] = f2bf(v);
    }
}

// ------------------------------------------------------------------
// FUSED layer-1: aggregate (mean) + x_dst gather -> LDS A-tile -> MFMA GEMM
//   h[64 rows][256] = relu([mean | x_dst] @ Bt0^T + bias)
// BM=64: 1408 blocks x 512 threads (8 waves). LDS ~43 KB -> 3 blocks/CU.
// Phase 1b lane map (R10 change): u = t&3 selects a 16B chunk WITHIN each
// 64B window (addr = u*16 + i*64), so the 4 adjacent lanes of a row-group
// cover one contiguous 64B segment per instruction -> 1 TA request instead
// of 4 (was q*128 + i*16, 128B-strided adjacent lanes). 8 requests/edge
// instead of 32 — attacks the R7-measured request-throughput wall.
// ------------------------------------------------------------------
__global__ __launch_bounds__(512, 4) void fused1_k(
    const float* __restrict__ X, const int* __restrict__ csr,
    const int* __restrict__ rstart, const int* __restrict__ cnt,
    const int* __restrict__ nid, const ushort* __restrict__ Bt,
    const float* __restrict__ bias, ushort* __restrict__ C) {
    __shared__ ushort As[64][264];  // [row][mean(0..127) | xdst(128..255)], +8 pad
    __shared__ ushort Bs[64][72];
    __shared__ int s_beg[64], s_num[64];

    int t = threadIdx.x;
    int row0 = blockIdx.x * 64;

    if (t < 64) {
        s_beg[t] = rstart[row0 + t];
        s_num[t] = cnt[row0 + t];
    }
    __syncthreads();

    // ---------- phase 1a: x_dst gather (8 threads/row, 16 cols each) ----------
    {
        int row = t >> 3, q = t & 7;
        int gr = nid[row0 + row];
        const float* gp = &X[(size_t)gr * F_IN + q * 16];
#pragma unroll
        for (int i = 0; i < 2; ++i) {
            float4 v0 = *(const float4*)(gp + i * 8);
            float4 v1 = *(const float4*)(gp + i * 8 + 4);
            short8 o;
            o[0] = (short)f2bf(v0.x); o[1] = (short)f2bf(v0.y);
            o[2] = (short)f2bf(v0.z); o[3] = (short)f2bf(v0.w);
            o[4] = (short)f2bf(v1.x); o[5] = (short)f2bf(v1.y);
            o[6] = (short)f2bf(v1.z); o[7] = (short)f2bf(v1.w);
            *(short8*)&As[row][F_IN + q * 16 + i * 8] = o;
        }
    }

    // ---------- phase 1b: edge aggregation, 2 passes of 32 rows ----------
    {
        int u = t & 3;             // 16B chunk within each 64B window
        int slot = (t >> 2) & 3;   // edge slot (lane bits 2..3)
        int rloc = t >> 4;         // row within pass [0,32)
#pragma unroll 1
        for (int pass = 0; pass < 2; ++pass) {
            int row = pass * 32 + rloc;
            int beg = s_beg[row], num = s_num[row];
            float acc[32] = {};
#pragma unroll 1
            for (int e = slot; e < num; e += 4) {
                int r = csr[beg + e];
                // lane u covers bytes u*16 + i*64 of the 512B row:
                // 4 adjacent lanes -> contiguous 64B per instruction.
                const float* rp = &X[(size_t)r * F_IN + u * 4];
#pragma unroll
                for (int i = 0; i < 8; ++i) {
                    float4 v = *(const float4*)(rp + i * 16);
                    acc[i * 4 + 0] += v.x;
                    acc[i * 4 + 1] += v.y;
                    acc[i * 4 + 2] += v.z;
                    acc[i * 4 + 3] += v.w;
                }
            }
            // combine the 4 slots (lane bits 2..3) via butterfly
#pragma unroll
            for (int i = 0; i < 32; ++i) {
                acc[i] += __shfl_xor(acc[i], 4);
                acc[i] += __shfl_xor(acc[i], 8);
            }
            if (slot == 0) {
                float inv = 1.f / (float)((num > 0) ? num : 1);
                // lane u holds cols {i*16 + u*4 .. +4}: 8 x 8B stores
#pragma unroll
                for (int i = 0; i < 8; ++i) {
                    ushort4 o;
                    o.x = f2bf(acc[i * 4 + 0] * inv);
                    o.y = f2bf(acc[i * 4 + 1] * inv);
                    o.z = f2bf(acc[i * 4 + 2] * inv);
                    o.w = f2bf(acc[i * 4 + 3] * inv);
                    *(ushort4*)&As[row][i * 16 + u * 4] = o;
                }
            }
        }
    }

    // ---------- phase 2: GEMM (Bs-staged, wave tile 32m x 16n) ----------
    int lane = t & 63;
    int w = t >> 6;
    int wm = w >> 2, wn2 = w & 3;  // 2(m) x 4(n) wave grid
    int lr = lane & 15, lj = lane >> 4;
    int bn = t >> 3, bk = (t & 7) * 8;  // B stage map: 64 n-rows x 64 k

    for (int nt = 0; nt < 4; ++nt) {
        f32x4 acc2[2] = {};
        for (int k0 = 0; k0 < 256; k0 += 64) {
            short8 bv = *(const short8*)&Bt[(size_t)(nt * 64 + bn) * 256 + k0 + bk];
            __syncthreads();  // As writes done (1st iter); prior Bs reads done
            *(short8*)&Bs[bn][bk] = bv;
            __syncthreads();
#pragma unroll
            for (int ks = 0; ks < 64; ks += 32) {
                short8 bf = *(const short8*)&Bs[wn2 * 16 + lr][ks + lj * 8];
#pragma unroll
                for (int mi = 0; mi < 2; ++mi) {
                    short8 af = *(const short8*)&As[wm * 32 + mi * 16 + lr][k0 + ks + lj * 8];
                    acc2[mi] = __builtin_amdgcn_mfma_f32_16x16x32_bf16(af, bf, acc2[mi], 0, 0, 0);
                }
            }
        }
        int c = nt * 64 + wn2 * 16 + lr;
        float bi = bias[c];
#pragma unroll
        for (int mi = 0; mi < 2; ++mi) {
#pragma unroll
            for (int j = 0; j < 4; ++j) {
                int r = row0 + wm * 32 + mi * 16 + lj * 4 + j;
                float v = acc2[mi][j] + bi;
                v = fmaxf(v, 0.f);
                C[(size_t)r * HID + c] = f2bf(v);
            }
        }
    }
}

// ------------------------------------------------------------------
// Mean aggregation (layer 2), vectorized 16B/lane, bf16 in.
// ------------------------------------------------------------------
template <int F>
__global__ __launch_bounds__(128) void agg_k(
    const ushort* __restrict__ Xh, const int* __restrict__ csr,
    const int* __restrict__ rstart, const int* __restrict__ cnt, int dofs,
    ushort* __restrict__ mean) {
    __shared__ float sh[128][8];
    int d = blockIdx.x;
    int t = threadIdx.x;
    int cg = t & 31, slot = t >> 5;
    int beg = rstart[dofs + d];
    int num = cnt[dofs + d];
    float acc[8] = {};
    for (int e = 0; e < num; e += 8) {
        int i0 = e + slot, i1 = e + 4 + slot;
        bool v0 = i0 < num, v1 = i1 < num;
        int r0 = v0 ? csr[beg + i0] : 0;
        int r1 = v1 ? csr[beg + i1] : 0;
        if (v0) {
            short8 x = *(const short8*)&Xh[(size_t)r0 * F + cg * 8];
#pragma unroll
            for (int i = 0; i < 8; ++i) acc[i] += bf2f((ushort)x[i]);
        }
        if (v1) {
            short8 x = *(const short8*)&Xh[(size_t)r1 * F + cg * 8];
#pragma unroll
            for (int i = 0; i < 8; ++i) acc[i] += bf2f((ushort)x[i]);
        }
    }
#pragma unroll
    for (int i = 0; i < 8; ++i) sh[t][i] = acc[i];
    __syncthreads();
    if (t < 32) {
        float inv = 1.f / (float)((num > 0) ? num : 1);
        short8 ov;
#pragma unroll
        for (int i = 0; i < 8; ++i) {
            float s = sh[t][i] + sh[t + 32][i] + sh[t + 64][i] + sh[t + 96][i];
            ov[i] = (short)f2bf(s * inv);
        }
        *(short8*)&mean[(size_t)d * F + t * 8] = ov;
    }
}

// ------------------------------------------------------------------
// bf16 MFMA concat-K GEMM (layer 2): C = [A0 | A1] @ Bt^T + bias
// ------------------------------------------------------------------
template <int BM, int KHALF, int NCOLS, bool RELU, bool OUT_BF16>
__global__ __launch_bounds__(256) void mgemm_k(
    const ushort* __restrict__ A0, const ushort* __restrict__ A1,
    const ushort* __restrict__ Bt, const float* __restrict__ bias,
    void* __restrict__ Cv, int M) {
    constexpr int MI = BM / 32;
    constexpr int TPR = 256 / BM;
    constexpr int AV = 64 / TPR / 8;
    __shared__ ushort As[BM][72];
    __shared__ ushort Bs[64][72];

    int t = threadIdx.x;
    int row0 = blockIdx.x * BM;
    int col0 = blockIdx.y * 64;
    int lane = t & 63;
    int w = t >> 6, wm = w >> 1, wn = w & 1;
    int lr = lane & 15;
    int lk = (lane >> 4) * 8;

    int ar = t / TPR, ac = (t % TPR) * (64 / TPR);
    int bn = t >> 2, bc = (t & 3) * 16;

    f32x4 acc[MI][2] = {};

    for (int k0 = 0; k0 < 2 * KHALF; k0 += 64) {
        const ushort* Asrc = (k0 < KHALF) ? A0 : A1;
        int kof = (k0 < KHALF) ? k0 : (k0 - KHALF);
        const ushort* ap = &Asrc[(size_t)(row0 + ar) * KHALF + kof + ac];
        const ushort* bp = &Bt[(size_t)(col0 + bn) * (2 * KHALF) + k0 + bc];
        short8 av[AV];
#pragma unroll
        for (int i = 0; i < AV; ++i) av[i] = *(const short8*)(ap + 8 * i);
        short8 bv0 = *(const short8*)(bp);
        short8 bv1 = *(const short8*)(bp + 8);
        __syncthreads();
#pragma unroll
        for (int i = 0; i < AV; ++i) *(short8*)&As[ar][ac + 8 * i] = av[i];
        *(short8*)&Bs[bn][bc + 0] = bv0;
        *(short8*)&Bs[bn][bc + 8] = bv1;
        __syncthreads();
#pragma unroll
        for (int ks = 0; ks < 64; ks += 32) {
            short8 bf0 = *(const short8*)&Bs[wn * 32 + lr][ks + lk];
            short8 bf1 = *(const short8*)&Bs[wn * 32 + 16 + lr][ks + lk];
#pragma unroll
            for (int mi = 0; mi < MI; ++mi) {
                short8 af = *(const short8*)&As[wm * (BM / 2) + mi * 16 + lr][ks + lk];
                acc[mi][0] = __builtin_amdgcn_mfma_f32_16x16x32_bf16(af, bf0, acc[mi][0], 0, 0, 0);
                acc[mi][1] = __builtin_amdgcn_mfma_f32_16x16x32_bf16(af, bf1, acc[mi][1], 0, 0, 0);
            }
        }
    }

    int orow = row0 + wm * (BM / 2);
    int ocol = col0 + wn * 32;
#pragma unroll
    for (int mi = 0; mi < MI; ++mi) {
#pragma unroll
        for (int ni = 0; ni < 2; ++ni) {
            int c = ocol + ni * 16 + lr;
            float bi = bias[c];
#pragma unroll
            for (int j = 0; j < 4; ++j) {
                int r = orow + mi * 16 + (lane >> 4) * 4 + j;
                float v = acc[mi][ni][j] + bi;
                if (RELU) v = fmaxf(v, 0.f);
                if (OUT_BF16)
                    ((ushort*)Cv)[(size_t)r * NCOLS + c] = f2bf(v);
                else
                    ((float*)Cv)[(size_t)r * NCOLS + c] = v;
            }
        }
    }
}

// ------------------------------------------------------------------
extern "C" void kernel_launch(void* const* d_in, const int* in_sizes, int n_in,
                              void* d_out, int out_size, void* d_ws, size_t ws_size,
                              hipStream_t stream) {
    const float* x_all = (const float*)d_in[0];
    const int* n_id = (const int*)d_in[1];
    const int* esrc0 = (const int*)d_in[2];
    const int* edst0 = (const int*)d_in[3];
    const int* esrc1 = (const int*)d_in[4];
    const int* edst1 = (const int*)d_in[5];
    const float* W_l0 = (const float*)d_in[6];
    const float* b_l0 = (const float*)d_in[7];
    const float* W_r0 = (const float*)d_in[8];
    const float* W_l1 = (const float*)d_in[9];
    const float* b_l1 = (const float*)d_in[10];
    const float* W_r1 = (const float*)d_in[11];

    char* ws = (char*)d_ws;
    size_t off = 0;
    auto alloc = [&](size_t bytes) {
        off = (off + 255) & ~(size_t)255;
        void* p = ws + off;
        off += bytes;
        return p;
    };
    int* cntcur = (int*)alloc((size_t)2 * NDT * 4);  // [cnt | cursor], one memset
    int* cnt = cntcur;
    int* cur = cntcur + NDT;
    int* rs = (int*)alloc((size_t)NDT * 4);
    int* csr = (int*)alloc((size_t)NET * 4);
    int* bsum = (int*)alloc(1024 * 4);
    int* boff = (int*)alloc(1024 * 4);
    ushort* h = (ushort*)alloc((size_t)ND0 * HID * 2);
    ushort* mean1 = (ushort*)alloc((size_t)ND1 * HID * 2);
    ushort* Bt0 = (ushort*)alloc((size_t)HID * (2 * F_IN) * 2);
    ushort* Bt1 = (ushort*)alloc((size_t)F_OUT * (2 * HID) * 2);

    hipMemsetAsync(cntcur, 0, (size_t)2 * NDT * 4, stream);

    // weight prep + CSR build (both layers combined)
    wtrans_all_k<<<512, 256, 0, stream>>>(W_l0, W_r0, W_l1, W_r1, Bt0, Bt1);
    hist_all_k<<<NET / 256, 256, 0, stream>>>(edst0, edst1, cnt);
    scan_part_k<<<NDT / 1024, 256, 0, stream>>>(cnt, rs, bsum, NDT);
    scan_part_k<<<1, 256, 0, stream>>>(bsum, boff, nullptr, NDT / 1024);
    scan_add_k<<<NDT / 256, 256, 0, stream>>>(rs, boff, NDT);
    scatter_all_k<<<NET / 256, 256, 0, stream>>>(esrc0, edst0, esrc1, edst1, n_id,
                                                 rs, cur, csr);

    // ---------------- Layer 1 (fused agg + gather + GEMM) ----------------
    fused1_k<<<ND0 / 64, 512, 0, stream>>>(x_all, csr, rs, cnt, n_id, Bt0, b_l0, h);

    // ---------------- Layer 2 ----------------
    agg_k<HID><<<ND1, 128, 0, stream>>>(h, csr, rs, cnt, ND0, mean1);
    mgemm_k<64, HID, F_OUT, false, false>
        <<<dim3(ND1 / 64, F_OUT / 64), 256, 0, stream>>>(mean1, h, Bt1, b_l1,
                                                         (float*)d_out, ND1);
}